// Round 7
// baseline (998.707 us; speedup 1.0000x reference)
//
#include <hip/hip_runtime.h>
#include <hip/hip_bf16.h>

#define NN 20000
#define NE 320000
#define LL 16
#define TT 64
#define HH 128

typedef __attribute__((ext_vector_type(8))) short short8v;
typedef __attribute__((ext_vector_type(4))) float f32x4;
#define MFMA_BF16(a,b,c) __builtin_amdgcn_mfma_f32_16x16x32_bf16(a,b,c,0,0,0)

__device__ inline unsigned short f32_to_bf16(float v) {
  unsigned int b = __float_as_uint(v);
  b += 0x7fffu + ((b >> 16) & 1u);
  return (unsigned short)(b >> 16);
}
__device__ inline float bf16_to_f32(unsigned short u) {
  return __uint_as_float(((unsigned int)u) << 16);
}
__device__ inline float fast_sigmoid(float x) {
  return __builtin_amdgcn_rcpf(1.f + __expf(-x));
}
__device__ inline float fast_tanh(float x) {
  float e = __expf(2.f * x);
  return 1.f - 2.f * __builtin_amdgcn_rcpf(e + 1.f);
}
__device__ inline unsigned int cvt_pk_bf16(float lo, float hi) {
  unsigned int r;
  asm("v_cvt_pk_bf16_f32 %0, %1, %2" : "=v"(r) : "v"(lo), "v"(hi));
  return r;
}
__device__ inline unsigned int combine2(unsigned int us, unsigned int ud) {
  float sl = __uint_as_float(us << 16);
  float sh = __uint_as_float(us & 0xffff0000u);
  float dl = __uint_as_float(ud << 16);
  float dh = __uint_as_float(ud & 0xffff0000u);
  return cvt_pk_bf16(fmaxf(sl + dl, 0.f), fmaxf(sh + dh, 0.f));
}

// ---------------- fused prep: all weight conversions in one kernel ----------------
__global__ void prep_k(
    const float* __restrict__ gwih, const float* __restrict__ gwhh,
    const float* __restrict__ rw1, const float* __restrict__ cw1,
    const float* __restrict__ conv2w,
    const float* __restrict__ lpw, const float* __restrict__ ltw, const float* __restrict__ liw,
    const float* __restrict__ lpb, const float* __restrict__ ltb, const float* __restrict__ lib,
    const float* __restrict__ gbih, const float* __restrict__ gbhh,
    unsigned short* __restrict__ wihB, unsigned short* __restrict__ whhB,
    unsigned short* __restrict__ rw1T, unsigned short* __restrict__ cw1T,
    unsigned short* __restrict__ conv2T,
    unsigned short* __restrict__ TposW, unsigned short* __restrict__ TtxtW,
    unsigned short* __restrict__ TimgW,
    float* __restrict__ bcomb, float* __restrict__ brz,
    float* __restrict__ binv, float* __restrict__ bhnv)
{
  int i = blockIdx.x * 256 + threadIdx.x;
  if (i < 24576) { wihB[i] = f32_to_bf16(gwih[i]); return; } i -= 24576;
  if (i < 49152) { whhB[i] = f32_to_bf16(gwhh[i]); return; } i -= 49152;
  if (i < 49152) { int c = i / 384, r = i - c * 384; rw1T[i] = f32_to_bf16(rw1[r * 128 + c]); return; } i -= 49152;
  if (i < 49152) { int c = i / 384, r = i - c * 384; cw1T[i] = f32_to_bf16(cw1[r * 128 + c]); return; } i -= 49152;
  if (i < 16384) { int c = i / 128, r = i - c * 128; conv2T[i] = f32_to_bf16(conv2w[r * 128 + c]); return; } i -= 16384;
  if (i < 32768) { int col = i / 128, k = i - col * 128;
    float v = (col < 128) ? lpw[k * 128 + col] : lpw[(128 + k) * 128 + (col - 128)];
    TposW[i] = f32_to_bf16(v); return; } i -= 32768;
  if (i < 32768) { int col = i / 128, k = i - col * 128;
    float v = (col < 128) ? ltw[k * 128 + col] : ltw[(128 + k) * 128 + (col - 128)];
    TtxtW[i] = f32_to_bf16(v); return; } i -= 32768;
  if (i < 65536) { int col = i / 256, k = i - col * 256;
    float v = (col < 128) ? liw[k * 128 + col] : liw[(256 + k) * 128 + (col - 128)];
    TimgW[i] = f32_to_bf16(v); return; } i -= 65536;
  if (i < 768) { int t = i >> 8, j = i & 255;
    const float* b = t == 0 ? lpb : t == 1 ? ltb : lib;
    bcomb[i] = (j < 128) ? 0.f : b[j - 128]; return; } i -= 768;
  if (i < 512) {
    if (i < 256) brz[i] = gbih[i] + gbhh[i];
    else if (i < 384) binv[i - 256] = gbih[i];
    else bhnv[i - 384] = gbhh[i - 128];
  }
}

__global__ void cvtf2_k(const float* __restrict__ in, unsigned int* __restrict__ out, int n2) {
  int i = blockIdx.x * 256 + threadIdx.x;
  if (i < n2) {
    float2 v = reinterpret_cast<const float2*>(in)[i];
    out[i] = cvt_pk_bf16(v.x, v.y);
  }
}

// ---------------- CSR build ----------------
__global__ void fill_zero_k(float* __restrict__ p, int n) {
  int i = blockIdx.x * 256 + threadIdx.x;
  if (i < n) p[i] = 0.f;
}

__global__ void histo_k(const int* __restrict__ eidx, int* __restrict__ ideg) {
  int e = blockIdx.x * 256 + threadIdx.x;
  if (e < NE) atomicAdd(&ideg[eidx[NE + e]], 1);
}

__global__ void scan_k(const int* __restrict__ ideg, int* __restrict__ rowptr) {
  __shared__ int sh[256];
  __shared__ int carry;
  const int tid = threadIdx.x;
  if (tid == 0) carry = 0;
  __syncthreads();
  for (int base = 0; base < NN; base += 256) {
    int v = (base + tid < NN) ? ideg[base + tid] : 0;
    sh[tid] = v;
    __syncthreads();
#pragma unroll
    for (int off = 1; off < 256; off <<= 1) {
      int t = (tid >= off) ? sh[tid - off] : 0;
      __syncthreads();
      sh[tid] += t;
      __syncthreads();
    }
    if (base + tid < NN) rowptr[base + tid] = carry + sh[tid] - v;
    __syncthreads();
    if (tid == 255) carry += sh[255];
    __syncthreads();
  }
  if (tid == 0) rowptr[NN] = carry;
}

__global__ void dinv_csr_k(const int* __restrict__ rowptr, float* __restrict__ dinv) {
  int i = blockIdx.x * 256 + threadIdx.x;
  if (i < NN) dinv[i] = rsqrtf((float)(rowptr[i + 1] - rowptr[i]) + 1.f);
}

__global__ void scatter_k(const int* __restrict__ eidx, int* __restrict__ cursor,
                          int* __restrict__ esrc_s, int* __restrict__ edst_s,
                          int* __restrict__ eorig_s) {
  int e = blockIdx.x * 256 + threadIdx.x;
  if (e >= NE) return;
  int s = eidx[e], d = eidx[NE + e];
  int pos = atomicAdd(&cursor[d], 1);
  esrc_s[pos] = s;
  edst_s[pos] = d;
  eorig_s[pos] = e;
}

// ---------------- conv1: xws1 = (x @ w1) * dinv[row], bf16 ----------------
__global__ void xw1_k(const float* __restrict__ x, const float* __restrict__ w,
                      const float* __restrict__ dinv, unsigned int* __restrict__ xws) {
  int i = blockIdx.x * 256 + threadIdx.x; // over NN*64 (2 cols per thread)
  if (i >= NN * 64) return;
  int n = i >> 6, c2 = (i & 63) * 2;
  float a0 = 0.f, a1 = 0.f;
#pragma unroll
  for (int k = 0; k < 8; ++k) {
    float xv = x[n * 8 + k];
    a0 += xv * w[k * 128 + c2];
    a1 += xv * w[k * 128 + c2 + 1];
  }
  float dn = dinv[n];
  xws[i] = cvt_pk_bf16(a0 * dn, a1 * dn);
}

// ---------------- atomic-free GCN aggregate over prescaled bf16 rows -----------
__global__ __launch_bounds__(256) void gcn_csr_k(
    const int* __restrict__ rowptr, const int* __restrict__ esrc_s,
    const unsigned int* __restrict__ xws, const float* __restrict__ dinv,
    const float* __restrict__ bias, unsigned int* __restrict__ outB)
{
  int node = blockIdx.x * 4 + (threadIdx.x >> 6);
  int lane = threadIdx.x & 63;
  if (node >= NN) return;
  float dd = dinv[node];
  int beg = rowptr[node], end = rowptr[node + 1];
  float a0 = 0.f, a1 = 0.f;
  int i = beg;
  for (; i + 1 < end; i += 2) {
    int s0 = esrc_s[i], s1 = esrc_s[i + 1];
    unsigned int u0 = xws[s0 * 64 + lane];
    unsigned int u1 = xws[s1 * 64 + lane];
    a0 += __uint_as_float(u0 << 16) + __uint_as_float(u1 << 16);
    a1 += __uint_as_float(u0 & 0xffff0000u) + __uint_as_float(u1 & 0xffff0000u);
  }
  if (i < end) {
    unsigned int u = xws[esrc_s[i] * 64 + lane];
    a0 += __uint_as_float(u << 16);
    a1 += __uint_as_float(u & 0xffff0000u);
  }
  unsigned int un = xws[node * 64 + lane];
  a0 += __uint_as_float(un << 16);
  a1 += __uint_as_float(un & 0xffff0000u);
  a0 = fmaxf(a0 * dd + bias[lane * 2], 0.f);
  a1 = fmaxf(a1 * dd + bias[lane * 2 + 1], 0.f);
  outB[node * 64 + lane] = cvt_pk_bf16(a0, a1);
}

// ---------------- direct-fragment MFMA GEMM (bf16 A, bf16 WT[col][K]) --------
template<int KDIM, int NCOLS, bool OUTBF16, bool ADDBIAS, bool SCALEROW>
__global__ __launch_bounds__(256) void gemm_mfma_k(
    const unsigned short* __restrict__ A, const unsigned short* __restrict__ WT,
    const float* __restrict__ bias, const float* __restrict__ rowscale,
    void* __restrict__ Cv, int M)
{
  const int tid = threadIdx.x;
  const int wid = tid >> 6, lane = tid & 63;
  const int l16 = lane & 15, lk = lane >> 4;
  const int bm = blockIdx.x * 128, bn = blockIdx.y * 128;
  const int wr = wid * 32;

  int row[2];
#pragma unroll
  for (int mf = 0; mf < 2; ++mf) {
    int r = bm + wr + mf * 16 + l16;
    row[mf] = r < M ? r : M - 1;
  }
  f32x4 acc[2][8];
#pragma unroll
  for (int mf = 0; mf < 2; ++mf)
#pragma unroll
    for (int nf = 0; nf < 8; ++nf) acc[mf][nf] = f32x4{0.f, 0.f, 0.f, 0.f};

#pragma unroll
  for (int kc = 0; kc < KDIM / 32; ++kc) {
    short8v a[2];
#pragma unroll
    for (int mf = 0; mf < 2; ++mf)
      a[mf] = *reinterpret_cast<const short8v*>(&A[(size_t)row[mf] * KDIM + kc * 32 + lk * 8]);
#pragma unroll
    for (int nf = 0; nf < 8; ++nf) {
      int col = bn + nf * 16 + l16;
      short8v b = *reinterpret_cast<const short8v*>(&WT[(size_t)col * KDIM + kc * 32 + lk * 8]);
      acc[0][nf] = MFMA_BF16(a[0], b, acc[0][nf]);
      acc[1][nf] = MFMA_BF16(a[1], b, acc[1][nf]);
    }
  }
#pragma unroll
  for (int mf = 0; mf < 2; ++mf)
#pragma unroll
    for (int nf = 0; nf < 8; ++nf) {
      int col = bn + nf * 16 + l16;
      float bb = ADDBIAS ? bias[col] : 0.f;
#pragma unroll
      for (int reg = 0; reg < 4; ++reg) {
        int r = bm + wr + mf * 16 + lk * 4 + reg;
        if (r < M) {
          float v = acc[mf][nf][reg] + bb;
          if (SCALEROW) v *= rowscale[r];
          if (OUTBF16) ((unsigned short*)Cv)[(size_t)r * NCOLS + col] = f32_to_bf16(v);
          else         ((float*)Cv)[(size_t)r * NCOLS + col] = v;
        }
      }
    }
}

// ---------------- fused persistent GRU (32 nodes/block, weights in registers) --
__global__ __launch_bounds__(256, 2) void gru_fused_k(
    const int* __restrict__ xtext, const float* __restrict__ embed,
    const unsigned short* __restrict__ wihB, const unsigned short* __restrict__ whhB,
    const float* __restrict__ brz, const float* __restrict__ binv, const float* __restrict__ bhnv,
    unsigned short* __restrict__ txt)
{
  __shared__ unsigned char hs[2][32 * 256];
  __shared__ unsigned char xs[32 * 128];
  const int tid = threadIdx.x;
  const int n0 = blockIdx.x * 32;
  const int wid = tid >> 6, lane = tid & 63;
  const int l16 = lane & 15, lk = lane >> 4;

  for (int i = tid; i < 32 * 256 / 4; i += 256) ((unsigned int*)hs[0])[i] = 0u;

  short8v wR[2][2], wZ[2][2], wN[2][2];
  short8v uR[2][4], uZ[2][4], uN[2][4];
  float bRr[2], bZr[2], bIr[2], bHr[2];
#pragma unroll
  for (int cf = 0; cf < 2; ++cf) {
    int col = wid * 32 + cf * 16 + l16;
#pragma unroll
    for (int ks = 0; ks < 2; ++ks) {
      wR[cf][ks] = *reinterpret_cast<const short8v*>(&wihB[(col      ) * 64 + ks * 32 + lk * 8]);
      wZ[cf][ks] = *reinterpret_cast<const short8v*>(&wihB[(col + 128) * 64 + ks * 32 + lk * 8]);
      wN[cf][ks] = *reinterpret_cast<const short8v*>(&wihB[(col + 256) * 64 + ks * 32 + lk * 8]);
    }
#pragma unroll
    for (int ks = 0; ks < 4; ++ks) {
      uR[cf][ks] = *reinterpret_cast<const short8v*>(&whhB[(col      ) * 128 + ks * 32 + lk * 8]);
      uZ[cf][ks] = *reinterpret_cast<const short8v*>(&whhB[(col + 128) * 128 + ks * 32 + lk * 8]);
      uN[cf][ks] = *reinterpret_cast<const short8v*>(&whhB[(col + 256) * 128 + ks * 32 + lk * 8]);
    }
    bRr[cf] = brz[col]; bZr[cf] = brz[128 + col];
    bIr[cf] = binv[col]; bHr[cf] = bhnv[col];
  }

  f32x4 txtacc[2][2];
#pragma unroll
  for (int mf = 0; mf < 2; ++mf)
#pragma unroll
    for (int cf = 0; cf < 2; ++cf) txtacc[mf][cf] = f32x4{0.f, 0.f, 0.f, 0.f};

  int cur = 0;
  for (int t = 0; t < LL; ++t) {
    __syncthreads();
    {
      const int k4 = tid & 15, r0 = tid >> 4;
#pragma unroll
      for (int rep = 0; rep < 2; ++rep) {
        int row = r0 + rep * 16;
        int n = n0 + row; if (n >= NN) n = NN - 1;
        int tok = xtext[n * LL + t];
        float4 v = *reinterpret_cast<const float4*>(&embed[(size_t)tok * TT + k4 * 4]);
        ushort4 w;
        w.x = f32_to_bf16(v.x); w.y = f32_to_bf16(v.y);
        w.z = f32_to_bf16(v.z); w.w = f32_to_bf16(v.w);
        *reinterpret_cast<ushort4*>(&xs[row * 128 + ((k4 * 8) ^ ((row & 7) << 4))]) = w;
      }
    }
    __syncthreads();

#pragma unroll
    for (int mf = 0; mf < 2; ++mf) {
      const int arow = mf * 16 + l16;
      const int asw = (arow & 7) << 4;
      short8v ax[2], ah[4];
#pragma unroll
      for (int ks = 0; ks < 2; ++ks)
        ax[ks] = *reinterpret_cast<const short8v*>(&xs[arow * 128 + ((ks * 64 + lk * 16) ^ asw)]);
#pragma unroll
      for (int ks = 0; ks < 4; ++ks)
        ah[ks] = *reinterpret_cast<const short8v*>(&hs[cur][arow * 256 + ((ks * 64 + lk * 16) ^ asw)]);

      f32x4 aR[2], aZ[2], aI[2], aHn[2];
#pragma unroll
      for (int cf = 0; cf < 2; ++cf) {
        aR[cf] = f32x4{0.f, 0.f, 0.f, 0.f}; aZ[cf] = f32x4{0.f, 0.f, 0.f, 0.f};
        aI[cf] = f32x4{0.f, 0.f, 0.f, 0.f}; aHn[cf] = f32x4{0.f, 0.f, 0.f, 0.f};
#pragma unroll
        for (int ks = 0; ks < 2; ++ks) {
          aR[cf] = MFMA_BF16(ax[ks], wR[cf][ks], aR[cf]);
          aZ[cf] = MFMA_BF16(ax[ks], wZ[cf][ks], aZ[cf]);
          aI[cf] = MFMA_BF16(ax[ks], wN[cf][ks], aI[cf]);
        }
#pragma unroll
        for (int ks = 0; ks < 4; ++ks) {
          aR[cf]  = MFMA_BF16(ah[ks], uR[cf][ks], aR[cf]);
          aZ[cf]  = MFMA_BF16(ah[ks], uZ[cf][ks], aZ[cf]);
          aHn[cf] = MFMA_BF16(ah[ks], uN[cf][ks], aHn[cf]);
        }
      }

#pragma unroll
      for (int cf = 0; cf < 2; ++cf) {
        const int j = wid * 32 + cf * 16 + l16;
#pragma unroll
        for (int reg = 0; reg < 4; ++reg) {
          const int row = mf * 16 + lk * 4 + reg;
          const int byte = row * 256 + ((j * 2) ^ ((row & 7) << 4));
          float hold = bf16_to_f32(*reinterpret_cast<unsigned short*>(&hs[cur][byte]));
          float rg = fast_sigmoid(aR[cf][reg] + bRr[cf]);
          float zg = fast_sigmoid(aZ[cf][reg] + bZr[cf]);
          float ng = fast_tanh(aI[cf][reg] + bIr[cf] + rg * (aHn[cf][reg] + bHr[cf]));
          float h2 = (1.f - zg) * ng + zg * hold;
          txtacc[mf][cf][reg] += h2;
          *reinterpret_cast<unsigned short*>(&hs[cur ^ 1][byte]) = f32_to_bf16(h2);
        }
      }
    }
    cur ^= 1;
  }

#pragma unroll
  for (int mf = 0; mf < 2; ++mf)
#pragma unroll
    for (int cf = 0; cf < 2; ++cf) {
      const int j = wid * 32 + cf * 16 + l16;
#pragma unroll
      for (int reg = 0; reg < 4; ++reg) {
        const int row = mf * 16 + lk * 4 + reg;
        const int n = n0 + row;
        if (n < NN) txt[(size_t)n * HH + j] = f32_to_bf16(txtacc[mf][cf][reg]);
      }
    }
}

// ---------------- fused edge heads: 16 edges/wave, <=128 VGPR, 4 waves/SIMD ----
// Wave = 16 edges x 128 cols x 2 heads (interleaved). Ring-2 chunk prefetch.
// acc 64 + ring 32 + misc ~ 116 regs -> 4 blocks/CU (2x occupancy of round 6).
__global__ __launch_bounds__(256, 4) void edge_mfma_k(
    const int* __restrict__ esrc_s, const int* __restrict__ edst_s,
    const int* __restrict__ eorig_s,
    const unsigned short* __restrict__ Tall,
    const unsigned short* __restrict__ rw1T, const float* __restrict__ rb1,
    const float* __restrict__ rw2, const float* __restrict__ rb2,
    const unsigned short* __restrict__ cw1T, const float* __restrict__ cb1,
    const float* __restrict__ cw2, const float* __restrict__ cb2,
    float* __restrict__ out)
{
  const int tid = threadIdx.x;
  const int wid = tid >> 6, lane = tid & 63;
  const int l16 = lane & 15, lk = lane >> 4;
  const int e0 = blockIdx.x * 64 + wid * 16;
  const int lkoff = lk * 8;

  const size_t soff = (size_t)esrc_s[e0 + l16] * 256;
  const size_t doff = (size_t)edst_s[e0 + l16] * 256 + 128;

  f32x4 acc0[8], acc1[8];
#pragma unroll
  for (int nf = 0; nf < 8; ++nf) {
    acc0[nf] = f32x4{0.f, 0.f, 0.f, 0.f};
    acc1[nf] = f32x4{0.f, 0.f, 0.f, 0.f};
  }

  uint4 sr[2][2], dr[2][2]; // ring-2 raw src/dst fragments

#define TB(c) (Tall + (size_t)((c) >> 1) * ((size_t)NN * 256) + ((c) & 1) * 64 + lkoff)
#define LD(c) { const unsigned short* tb = TB(c); \
  sr[(c) & 1][0] = *reinterpret_cast<const uint4*>(tb + soff); \
  sr[(c) & 1][1] = *reinterpret_cast<const uint4*>(tb + soff + 32); \
  dr[(c) & 1][0] = *reinterpret_cast<const uint4*>(tb + doff); \
  dr[(c) & 1][1] = *reinterpret_cast<const uint4*>(tb + doff + 32); }
#define PROC(c) { \
  _Pragma("unroll") for (int ks = 0; ks < 2; ++ks) { \
    uint4 s = sr[(c) & 1][ks], d = dr[(c) & 1][ks]; \
    unsigned int afr[4]; \
    afr[0] = combine2(s.x, d.x); afr[1] = combine2(s.y, d.y); \
    afr[2] = combine2(s.z, d.z); afr[3] = combine2(s.w, d.w); \
    short8v a = *reinterpret_cast<short8v*>(afr); \
    int kglob = (c) * 64 + ks * 32 + lkoff; \
    _Pragma("unroll") for (int nf = 0; nf < 8; ++nf) { \
      int col = nf * 16 + l16; \
      short8v br = *reinterpret_cast<const short8v*>(&rw1T[(size_t)col * 384 + kglob]); \
      acc0[nf] = MFMA_BF16(a, br, acc0[nf]); \
      short8v bc = *reinterpret_cast<const short8v*>(&cw1T[(size_t)col * 384 + kglob]); \
      acc1[nf] = MFMA_BF16(a, bc, acc1[nf]); \
    } \
  } }

  LD(0)
  LD(1)
  PROC(0) LD(2)
  PROC(1) LD(3)
  PROC(2) LD(4)
  PROC(3) LD(5)
  PROC(4)
  PROC(5)
#undef TB
#undef LD
#undef PROC

  // epilogue: both heads; layer2 + log_softmax via 16-lane shfl reduce
#pragma unroll
  for (int h = 0; h < 2; ++h) {
    const f32x4* ac = h ? acc1 : acc0;
    const float* b1 = h ? cb1 : rb1;
    const float* w2 = h ? cw2 : rw2;
    const float* b2 = h ? cb2 : rb2;
#pragma unroll
    for (int reg = 0; reg < 4; ++reg) {
      float p0 = 0.f, p1 = 0.f;
#pragma unroll
      for (int nf = 0; nf < 8; ++nf) {
        int col = nf * 16 + l16;
        float hv = fmaxf(ac[nf][reg] + b1[col], 0.f);
        p0 += hv * w2[col * 2];
        p1 += hv * w2[col * 2 + 1];
      }
#pragma unroll
      for (int m = 1; m < 16; m <<= 1) {
        p0 += __shfl_xor(p0, m);
        p1 += __shfl_xor(p1, m);
      }
      if (l16 == 0) {
        int orig = eorig_s[e0 + lk * 4 + reg];
        float l0 = p0 + b2[0], l1 = p1 + b2[1];
        float mx = fmaxf(l0, l1);
        float lse = mx + __logf(__expf(l0 - mx) + __expf(l1 - mx));
        float2 o2 = make_float2(l0 - lse, l1 - lse);
        *reinterpret_cast<float2*>(&out[(size_t)h * 2 * NE + (size_t)orig * 2]) = o2;
      }
    }
  }
}

// ---------------- launch ----------------
extern "C" void kernel_launch(void* const* d_in, const int* in_sizes, int n_in,
                              void* d_out, int out_size, void* d_ws, size_t ws_size,
                              hipStream_t stream)
{
  const float* x       = (const float*)d_in[0];
  const int*   eidx    = (const int*)  d_in[1];
  const int*   xtext   = (const int*)  d_in[2];
  const float* imgf    = (const float*)d_in[3];
  const float* conv1_w = (const float*)d_in[4];
  const float* conv1_b = (const float*)d_in[5];
  const float* conv2_w = (const float*)d_in[6];
  const float* conv2_b = (const float*)d_in[7];
  const float* embed   = (const float*)d_in[8];
  const float* gwih    = (const float*)d_in[9];
  const float* gwhh    = (const float*)d_in[10];
  const float* gbih    = (const float*)d_in[11];
  const float* gbhh    = (const float*)d_in[12];
  const float* lpw     = (const float*)d_in[13];
  const float* lpb     = (const float*)d_in[14];
  const float* ltw     = (const float*)d_in[15];
  const float* ltb     = (const float*)d_in[16];
  const float* liw     = (const float*)d_in[17];
  const float* lib     = (const float*)d_in[18];
  const float* rw1     = (const float*)d_in[19];
  const float* rb1     = (const float*)d_in[20];
  const float* rw2     = (const float*)d_in[21];
  const float* rb2     = (const float*)d_in[22];
  const float* cw1     = (const float*)d_in[23];
  const float* cb1     = (const float*)d_in[24];
  const float* cw2     = (const float*)d_in[25];
  const float* cb2     = (const float*)d_in[26];
  float* out = (float*)d_out;

  char* w8 = (char*)d_ws;
  size_t off = 0;
  auto balloc = [&](size_t bytes) { void* p = w8 + off; off = (off + bytes + 255) & ~(size_t)255; return p; };
  float*          dinv   = (float*)balloc(NN * 4);
  int*            ideg   = (int*)balloc((NN + 1) * 4);
  int*            rowptr = (int*)balloc((NN + 1) * 4);
  int*            cursor = (int*)balloc((NN + 1) * 4);
  int*            esrc_s = (int*)balloc((size_t)NE * 4);
  int*            edst_s = (int*)balloc((size_t)NE * 4);
  int*            eorig_s= (int*)balloc((size_t)NE * 4);
  unsigned int*   xwsB   = (unsigned int*)balloc((size_t)NN * 64 * 4);
  unsigned int*   nodeB  = (unsigned int*)balloc((size_t)NN * 64 * 4);
  unsigned short* txtB   = (unsigned short*)balloc((size_t)NN * HH * 2);
  unsigned short* imgB   = (unsigned short*)balloc((size_t)NN * 256 * 2);
  unsigned short* Tall   = (unsigned short*)balloc((size_t)3 * NN * 256 * 2);
  unsigned short* wihB   = (unsigned short*)balloc(384 * 64 * 2);
  unsigned short* whhB   = (unsigned short*)balloc(384 * 128 * 2);
  unsigned short* rw1T   = (unsigned short*)balloc(384 * 128 * 2);
  unsigned short* cw1T   = (unsigned short*)balloc(384 * 128 * 2);
  unsigned short* conv2T = (unsigned short*)balloc(128 * 128 * 2);
  unsigned short* TposW  = (unsigned short*)balloc(256 * 128 * 2);
  unsigned short* TtxtW  = (unsigned short*)balloc(256 * 128 * 2);
  unsigned short* TimgW  = (unsigned short*)balloc(256 * 256 * 2);
  float*          bcomb  = (float*)balloc(768 * 4);
  float*          brz    = (float*)balloc(256 * 4);
  float*          binv   = (float*)balloc(128 * 4);
  float*          bhnv   = (float*)balloc(128 * 4);

  dim3 b256(256);
  auto cdiv = [](int a, int b) { return (a + b - 1) / b; };
  const int MB = cdiv(NN, 128); // 157

  // ---- fused weight prep + img cast ----
  prep_k<<<cdiv(320768, 256), b256, 0, stream>>>(
      gwih, gwhh, rw1, cw1, conv2_w, lpw, ltw, liw, lpb, ltb, lib, gbih, gbhh,
      wihB, whhB, rw1T, cw1T, conv2T, TposW, TtxtW, TimgW, bcomb, brz, binv, bhnv);
  cvtf2_k<<<cdiv(NN * 128, 256), b256, 0, stream>>>(imgf, (unsigned int*)imgB, NN * 128);

  // ---- dst-sorted CSR + dinv ----
  fill_zero_k<<<cdiv(NN + 1, 256), b256, 0, stream>>>((float*)ideg, NN + 1);
  histo_k<<<cdiv(NE, 256), b256, 0, stream>>>(eidx, ideg);
  scan_k<<<1, b256, 0, stream>>>(ideg, rowptr);
  dinv_csr_k<<<cdiv(NN, 256), b256, 0, stream>>>(rowptr, dinv);
  hipMemcpyAsync(cursor, rowptr, (NN + 1) * sizeof(int), hipMemcpyDeviceToDevice, stream);
  scatter_k<<<cdiv(NE, 256), b256, 0, stream>>>(eidx, cursor, esrc_s, edst_s, eorig_s);

  // ---- GCN layer 1: prescaled bf16 rows -> CSR sum ----
  xw1_k<<<cdiv(NN * 64, 256), b256, 0, stream>>>(x, conv1_w, dinv, xwsB);
  gcn_csr_k<<<cdiv(NN, 4), b256, 0, stream>>>(rowptr, esrc_s, xwsB, dinv, conv1_b, nodeB);

  // ---- GCN layer 2: MFMA (bf16 out, row-prescaled) -> CSR sum ----
  gemm_mfma_k<128, 128, true, false, true><<<dim3(MB, 1), b256, 0, stream>>>(
      (const unsigned short*)nodeB, conv2T, nullptr, dinv, xwsB, NN);
  gcn_csr_k<<<cdiv(NN, 4), b256, 0, stream>>>(rowptr, esrc_s, xwsB, dinv, conv2_b, nodeB);

  // ---- GRU -> txt bf16 ----
  gru_fused_k<<<NN / 32, b256, 0, stream>>>(xtext, embed, wihB, whhB, brz, binv, bhnv, txtB);

  // ---- node tables (bf16, combined src|dst cols) ----
  gemm_mfma_k<128, 256, true, true, false><<<dim3(MB, 2), b256, 0, stream>>>(
      (const unsigned short*)nodeB, TposW, bcomb, nullptr, Tall, NN);
  gemm_mfma_k<128, 256, true, true, false><<<dim3(MB, 2), b256, 0, stream>>>(
      txtB, TtxtW, bcomb + 256, nullptr, Tall + (size_t)NN * 256, NN);
  gemm_mfma_k<256, 256, true, true, false><<<dim3(MB, 2), b256, 0, stream>>>(
      imgB, TimgW, bcomb + 512, nullptr, Tall + (size_t)2 * NN * 256, NN);

  // ---- fused edge heads + log_softmax (dst-sorted order) ----
  edge_mfma_k<<<NE / 64, b256, 0, stream>>>(esrc_s, edst_s, eorig_s, Tall,
                                            rw1T, rb1, rw2, rb2, cw1T, cb1, cw2, cb2, out);
}

// Round 9
// 827.792 us; speedup vs baseline: 1.2065x; 1.2065x over previous
//
#include <hip/hip_runtime.h>
#include <hip/hip_bf16.h>

#define NN 20000
#define NE 320000
#define LL 16
#define TT 64
#define HH 128

typedef __attribute__((ext_vector_type(8))) short short8v;
typedef __attribute__((ext_vector_type(4))) float f32x4;
#define MFMA_BF16(a,b,c) __builtin_amdgcn_mfma_f32_16x16x32_bf16(a,b,c,0,0,0)

__device__ inline unsigned short f32_to_bf16(float v) {
  unsigned int b = __float_as_uint(v);
  b += 0x7fffu + ((b >> 16) & 1u);
  return (unsigned short)(b >> 16);
}
__device__ inline float bf16_to_f32(unsigned short u) {
  return __uint_as_float(((unsigned int)u) << 16);
}
__device__ inline float fast_sigmoid(float x) {
  return __builtin_amdgcn_rcpf(1.f + __expf(-x));
}
__device__ inline float fast_tanh(float x) {
  float e = __expf(2.f * x);
  return 1.f - 2.f * __builtin_amdgcn_rcpf(e + 1.f);
}
__device__ inline unsigned int cvt_pk_bf16(float lo, float hi) {
  unsigned int r;
  asm("v_cvt_pk_bf16_f32 %0, %1, %2" : "=v"(r) : "v"(lo), "v"(hi));
  return r;
}
__device__ inline unsigned int combine2(unsigned int us, unsigned int ud) {
  float sl = __uint_as_float(us << 16);
  float sh = __uint_as_float(us & 0xffff0000u);
  float dl = __uint_as_float(ud << 16);
  float dh = __uint_as_float(ud & 0xffff0000u);
  return cvt_pk_bf16(fmaxf(sl + dl, 0.f), fmaxf(sh + dh, 0.f));
}

// ---------------- fused prep ----------------
__global__ void prep_k(
    const float* __restrict__ gwih, const float* __restrict__ gwhh,
    const float* __restrict__ rw1, const float* __restrict__ cw1,
    const float* __restrict__ conv2w,
    const float* __restrict__ lpw, const float* __restrict__ ltw, const float* __restrict__ liw,
    const float* __restrict__ lpb, const float* __restrict__ ltb, const float* __restrict__ lib,
    const float* __restrict__ gbih, const float* __restrict__ gbhh,
    unsigned short* __restrict__ wihB, unsigned short* __restrict__ whhB,
    unsigned short* __restrict__ rw1T, unsigned short* __restrict__ cw1T,
    unsigned short* __restrict__ conv2T,
    unsigned short* __restrict__ TposW, unsigned short* __restrict__ TtxtW,
    unsigned short* __restrict__ TimgW,
    float* __restrict__ bcomb, float* __restrict__ brz,
    float* __restrict__ binv, float* __restrict__ bhnv)
{
  int i = blockIdx.x * 256 + threadIdx.x;
  if (i < 24576) { wihB[i] = f32_to_bf16(gwih[i]); return; } i -= 24576;
  if (i < 49152) { whhB[i] = f32_to_bf16(gwhh[i]); return; } i -= 49152;
  if (i < 49152) { int c = i / 384, r = i - c * 384; rw1T[i] = f32_to_bf16(rw1[r * 128 + c]); return; } i -= 49152;
  if (i < 49152) { int c = i / 384, r = i - c * 384; cw1T[i] = f32_to_bf16(cw1[r * 128 + c]); return; } i -= 49152;
  if (i < 16384) { int c = i / 128, r = i - c * 128; conv2T[i] = f32_to_bf16(conv2w[r * 128 + c]); return; } i -= 16384;
  if (i < 32768) { int col = i / 128, k = i - col * 128;
    float v = (col < 128) ? lpw[k * 128 + col] : lpw[(128 + k) * 128 + (col - 128)];
    TposW[i] = f32_to_bf16(v); return; } i -= 32768;
  if (i < 32768) { int col = i / 128, k = i - col * 128;
    float v = (col < 128) ? ltw[k * 128 + col] : ltw[(128 + k) * 128 + (col - 128)];
    TtxtW[i] = f32_to_bf16(v); return; } i -= 32768;
  if (i < 65536) { int col = i / 256, k = i - col * 256;
    float v = (col < 128) ? liw[k * 128 + col] : liw[(256 + k) * 128 + (col - 128)];
    TimgW[i] = f32_to_bf16(v); return; } i -= 65536;
  if (i < 768) { int t = i >> 8, j = i & 255;
    const float* b = t == 0 ? lpb : t == 1 ? ltb : lib;
    bcomb[i] = (j < 128) ? 0.f : b[j - 128]; return; } i -= 768;
  if (i < 512) {
    if (i < 256) brz[i] = gbih[i] + gbhh[i];
    else if (i < 384) binv[i - 256] = gbih[i];
    else bhnv[i - 384] = gbhh[i - 128];
  }
}

__global__ void cvtf2_k(const float* __restrict__ in, unsigned int* __restrict__ out, int n2) {
  int i = blockIdx.x * 256 + threadIdx.x;
  if (i < n2) {
    float2 v = reinterpret_cast<const float2*>(in)[i];
    out[i] = cvt_pk_bf16(v.x, v.y);
  }
}

// ---------------- CSR build ----------------
__global__ void fill_zero_k(float* __restrict__ p, int n) {
  int i = blockIdx.x * 256 + threadIdx.x;
  if (i < n) p[i] = 0.f;
}

__global__ void histo_k(const int* __restrict__ eidx, int* __restrict__ ideg) {
  int e = blockIdx.x * 256 + threadIdx.x;
  if (e < NE) atomicAdd(&ideg[eidx[NE + e]], 1);
}

__global__ void scan_k(const int* __restrict__ ideg, int* __restrict__ rowptr) {
  __shared__ int sh[256];
  __shared__ int carry;
  const int tid = threadIdx.x;
  if (tid == 0) carry = 0;
  __syncthreads();
  for (int base = 0; base < NN; base += 256) {
    int v = (base + tid < NN) ? ideg[base + tid] : 0;
    sh[tid] = v;
    __syncthreads();
#pragma unroll
    for (int off = 1; off < 256; off <<= 1) {
      int t = (tid >= off) ? sh[tid - off] : 0;
      __syncthreads();
      sh[tid] += t;
      __syncthreads();
    }
    if (base + tid < NN) rowptr[base + tid] = carry + sh[tid] - v;
    __syncthreads();
    if (tid == 255) carry += sh[255];
    __syncthreads();
  }
  if (tid == 0) rowptr[NN] = carry;
}

__global__ void dinv_csr_k(const int* __restrict__ rowptr, float* __restrict__ dinv) {
  int i = blockIdx.x * 256 + threadIdx.x;
  if (i < NN) dinv[i] = rsqrtf((float)(rowptr[i + 1] - rowptr[i]) + 1.f);
}

__global__ void scatter_k(const int* __restrict__ eidx, int* __restrict__ cursor,
                          int* __restrict__ esrc_s, int* __restrict__ edst_s,
                          int* __restrict__ eorig_s) {
  int e = blockIdx.x * 256 + threadIdx.x;
  if (e >= NE) return;
  int s = eidx[e], d = eidx[NE + e];
  int pos = atomicAdd(&cursor[d], 1);
  esrc_s[pos] = s;
  edst_s[pos] = d;
  eorig_s[pos] = e;
}

// ---------------- conv1: xws1 = (x @ w1) * dinv[row], bf16 ----------------
__global__ void xw1_k(const float* __restrict__ x, const float* __restrict__ w,
                      const float* __restrict__ dinv, unsigned int* __restrict__ xws) {
  int i = blockIdx.x * 256 + threadIdx.x;
  if (i >= NN * 64) return;
  int n = i >> 6, c2 = (i & 63) * 2;
  float a0 = 0.f, a1 = 0.f;
#pragma unroll
  for (int k = 0; k < 8; ++k) {
    float xv = x[n * 8 + k];
    a0 += xv * w[k * 128 + c2];
    a1 += xv * w[k * 128 + c2 + 1];
  }
  float dn = dinv[n];
  xws[i] = cvt_pk_bf16(a0 * dn, a1 * dn);
}

// ---------------- atomic-free GCN aggregate over prescaled bf16 rows -----------
__global__ __launch_bounds__(256) void gcn_csr_k(
    const int* __restrict__ rowptr, const int* __restrict__ esrc_s,
    const unsigned int* __restrict__ xws, const float* __restrict__ dinv,
    const float* __restrict__ bias, unsigned int* __restrict__ outB)
{
  int node = blockIdx.x * 4 + (threadIdx.x >> 6);
  int lane = threadIdx.x & 63;
  if (node >= NN) return;
  float dd = dinv[node];
  int beg = rowptr[node], end = rowptr[node + 1];
  float a0 = 0.f, a1 = 0.f;
  int i = beg;
  for (; i + 1 < end; i += 2) {
    int s0 = esrc_s[i], s1 = esrc_s[i + 1];
    unsigned int u0 = xws[s0 * 64 + lane];
    unsigned int u1 = xws[s1 * 64 + lane];
    a0 += __uint_as_float(u0 << 16) + __uint_as_float(u1 << 16);
    a1 += __uint_as_float(u0 & 0xffff0000u) + __uint_as_float(u1 & 0xffff0000u);
  }
  if (i < end) {
    unsigned int u = xws[esrc_s[i] * 64 + lane];
    a0 += __uint_as_float(u << 16);
    a1 += __uint_as_float(u & 0xffff0000u);
  }
  unsigned int un = xws[node * 64 + lane];
  a0 += __uint_as_float(un << 16);
  a1 += __uint_as_float(un & 0xffff0000u);
  a0 = fmaxf(a0 * dd + bias[lane * 2], 0.f);
  a1 = fmaxf(a1 * dd + bias[lane * 2 + 1], 0.f);
  outB[node * 64 + lane] = cvt_pk_bf16(a0, a1);
}

// ---------------- direct-fragment MFMA GEMM, BM=64 tiles ----------------------
// block 256 = 4 waves; each wave 16 rows x 128 cols. grid (cdiv(M,64), NCOLS/128)
template<int KDIM, int NCOLS, bool OUTBF16, bool ADDBIAS, bool SCALEROW>
__global__ __launch_bounds__(256) void gemm_mfma_k(
    const unsigned short* __restrict__ A, const unsigned short* __restrict__ WT,
    const float* __restrict__ bias, const float* __restrict__ rowscale,
    void* __restrict__ Cv, int M)
{
  const int tid = threadIdx.x;
  const int wid = tid >> 6, lane = tid & 63;
  const int l16 = lane & 15, lk = lane >> 4;
  const int bm = blockIdx.x * 64, bn = blockIdx.y * 128;

  int r = bm + wid * 16 + l16;
  int row = r < M ? r : M - 1;
  f32x4 acc[8];
#pragma unroll
  for (int nf = 0; nf < 8; ++nf) acc[nf] = f32x4{0.f, 0.f, 0.f, 0.f};

#pragma unroll
  for (int kc = 0; kc < KDIM / 32; ++kc) {
    short8v a = *reinterpret_cast<const short8v*>(&A[(size_t)row * KDIM + kc * 32 + lk * 8]);
#pragma unroll
    for (int nf = 0; nf < 8; ++nf) {
      int col = bn + nf * 16 + l16;
      short8v b = *reinterpret_cast<const short8v*>(&WT[(size_t)col * KDIM + kc * 32 + lk * 8]);
      acc[nf] = MFMA_BF16(a, b, acc[nf]);
    }
  }
#pragma unroll
  for (int nf = 0; nf < 8; ++nf) {
    int col = bn + nf * 16 + l16;
    float bb = ADDBIAS ? bias[col] : 0.f;
#pragma unroll
    for (int reg = 0; reg < 4; ++reg) {
      int rr = bm + wid * 16 + lk * 4 + reg;
      if (rr < M) {
        float v = acc[nf][reg] + bb;
        if (SCALEROW) v *= rowscale[rr];
        if (OUTBF16) ((unsigned short*)Cv)[(size_t)rr * NCOLS + col] = f32_to_bf16(v);
        else         ((float*)Cv)[(size_t)rr * NCOLS + col] = v;
      }
    }
  }
}

// ---------------- fused persistent GRU (32 nodes/block, weights in registers) --
__global__ __launch_bounds__(256, 2) void gru_fused_k(
    const int* __restrict__ xtext, const float* __restrict__ embed,
    const unsigned short* __restrict__ wihB, const unsigned short* __restrict__ whhB,
    const float* __restrict__ brz, const float* __restrict__ binv, const float* __restrict__ bhnv,
    unsigned short* __restrict__ txt)
{
  __shared__ unsigned char hs[2][32 * 256];
  __shared__ unsigned char xs[32 * 128];
  const int tid = threadIdx.x;
  const int n0 = blockIdx.x * 32;
  const int wid = tid >> 6, lane = tid & 63;
  const int l16 = lane & 15, lk = lane >> 4;

  for (int i = tid; i < 32 * 256 / 4; i += 256) ((unsigned int*)hs[0])[i] = 0u;

  short8v wR[2][2], wZ[2][2], wN[2][2];
  short8v uR[2][4], uZ[2][4], uN[2][4];
  float bRr[2], bZr[2], bIr[2], bHr[2];
#pragma unroll
  for (int cf = 0; cf < 2; ++cf) {
    int col = wid * 32 + cf * 16 + l16;
#pragma unroll
    for (int ks = 0; ks < 2; ++ks) {
      wR[cf][ks] = *reinterpret_cast<const short8v*>(&wihB[(col      ) * 64 + ks * 32 + lk * 8]);
      wZ[cf][ks] = *reinterpret_cast<const short8v*>(&wihB[(col + 128) * 64 + ks * 32 + lk * 8]);
      wN[cf][ks] = *reinterpret_cast<const short8v*>(&wihB[(col + 256) * 64 + ks * 32 + lk * 8]);
    }
#pragma unroll
    for (int ks = 0; ks < 4; ++ks) {
      uR[cf][ks] = *reinterpret_cast<const short8v*>(&whhB[(col      ) * 128 + ks * 32 + lk * 8]);
      uZ[cf][ks] = *reinterpret_cast<const short8v*>(&whhB[(col + 128) * 128 + ks * 32 + lk * 8]);
      uN[cf][ks] = *reinterpret_cast<const short8v*>(&whhB[(col + 256) * 128 + ks * 32 + lk * 8]);
    }
    bRr[cf] = brz[col]; bZr[cf] = brz[128 + col];
    bIr[cf] = binv[col]; bHr[cf] = bhnv[col];
  }

  f32x4 txtacc[2][2];
#pragma unroll
  for (int mf = 0; mf < 2; ++mf)
#pragma unroll
    for (int cf = 0; cf < 2; ++cf) txtacc[mf][cf] = f32x4{0.f, 0.f, 0.f, 0.f};

  int cur = 0;
  for (int t = 0; t < LL; ++t) {
    __syncthreads();
    {
      const int k4 = tid & 15, r0 = tid >> 4;
#pragma unroll
      for (int rep = 0; rep < 2; ++rep) {
        int row = r0 + rep * 16;
        int n = n0 + row; if (n >= NN) n = NN - 1;
        int tok = xtext[n * LL + t];
        float4 v = *reinterpret_cast<const float4*>(&embed[(size_t)tok * TT + k4 * 4]);
        ushort4 w;
        w.x = f32_to_bf16(v.x); w.y = f32_to_bf16(v.y);
        w.z = f32_to_bf16(v.z); w.w = f32_to_bf16(v.w);
        *reinterpret_cast<ushort4*>(&xs[row * 128 + ((k4 * 8) ^ ((row & 7) << 4))]) = w;
      }
    }
    __syncthreads();

#pragma unroll
    for (int mf = 0; mf < 2; ++mf) {
      const int arow = mf * 16 + l16;
      const int asw = (arow & 7) << 4;
      short8v ax[2], ah[4];
#pragma unroll
      for (int ks = 0; ks < 2; ++ks)
        ax[ks] = *reinterpret_cast<const short8v*>(&xs[arow * 128 + ((ks * 64 + lk * 16) ^ asw)]);
#pragma unroll
      for (int ks = 0; ks < 4; ++ks)
        ah[ks] = *reinterpret_cast<const short8v*>(&hs[cur][arow * 256 + ((ks * 64 + lk * 16) ^ asw)]);

      f32x4 aR[2], aZ[2], aI[2], aHn[2];
#pragma unroll
      for (int cf = 0; cf < 2; ++cf) {
        aR[cf] = f32x4{0.f, 0.f, 0.f, 0.f}; aZ[cf] = f32x4{0.f, 0.f, 0.f, 0.f};
        aI[cf] = f32x4{0.f, 0.f, 0.f, 0.f}; aHn[cf] = f32x4{0.f, 0.f, 0.f, 0.f};
#pragma unroll
        for (int ks = 0; ks < 2; ++ks) {
          aR[cf] = MFMA_BF16(ax[ks], wR[cf][ks], aR[cf]);
          aZ[cf] = MFMA_BF16(ax[ks], wZ[cf][ks], aZ[cf]);
          aI[cf] = MFMA_BF16(ax[ks], wN[cf][ks], aI[cf]);
        }
#pragma unroll
        for (int ks = 0; ks < 4; ++ks) {
          aR[cf]  = MFMA_BF16(ah[ks], uR[cf][ks], aR[cf]);
          aZ[cf]  = MFMA_BF16(ah[ks], uZ[cf][ks], aZ[cf]);
          aHn[cf] = MFMA_BF16(ah[ks], uN[cf][ks], aHn[cf]);
        }
      }

#pragma unroll
      for (int cf = 0; cf < 2; ++cf) {
        const int j = wid * 32 + cf * 16 + l16;
#pragma unroll
        for (int reg = 0; reg < 4; ++reg) {
          const int row = mf * 16 + lk * 4 + reg;
          const int byte = row * 256 + ((j * 2) ^ ((row & 7) << 4));
          float hold = bf16_to_f32(*reinterpret_cast<unsigned short*>(&hs[cur][byte]));
          float rg = fast_sigmoid(aR[cf][reg] + bRr[cf]);
          float zg = fast_sigmoid(aZ[cf][reg] + bZr[cf]);
          float ng = fast_tanh(aI[cf][reg] + bIr[cf] + rg * (aHn[cf][reg] + bHr[cf]));
          float h2 = (1.f - zg) * ng + zg * hold;
          txtacc[mf][cf][reg] += h2;
          *reinterpret_cast<unsigned short*>(&hs[cur ^ 1][byte]) = f32_to_bf16(h2);
        }
      }
    }
    cur ^= 1;
  }

#pragma unroll
  for (int mf = 0; mf < 2; ++mf)
#pragma unroll
    for (int cf = 0; cf < 2; ++cf) {
      const int j = wid * 32 + cf * 16 + l16;
#pragma unroll
      for (int reg = 0; reg < 4; ++reg) {
        const int row = mf * 16 + lk * 4 + reg;
        const int n = n0 + row;
        if (n < NN) txt[(size_t)n * HH + j] = f32_to_bf16(txtacc[mf][cf][reg]);
      }
    }
}

// ---------------- fused edge heads (round-6 structure + bijective XCD swizzle) --
// Block: 128 edges, 4 waves x 32 edges (2 mf). Src burst af[6], dst ring-2.
// Head0 interleaved with loads; head1 pure-register under setprio(1).
__global__ __launch_bounds__(256, 2) void edge_mfma_k(
    const int* __restrict__ esrc_s, const int* __restrict__ edst_s,
    const int* __restrict__ eorig_s,
    const unsigned short* __restrict__ Tall,
    const unsigned short* __restrict__ rw1T, const float* __restrict__ rb1,
    const float* __restrict__ rw2, const float* __restrict__ rb2,
    const unsigned short* __restrict__ cw1T, const float* __restrict__ cb1,
    const float* __restrict__ cw2, const float* __restrict__ cb2,
    float* __restrict__ out)
{
  const int tid = threadIdx.x;
  // bijective XCD-chunked swizzle over 2500 blocks (q=312, r=4)
  const int bid = blockIdx.x;
  const int xcd = bid & 7, bi = bid >> 3;
  const int swz = (xcd < 4 ? xcd * 313 : 4 * 313 + (xcd - 4) * 312) + bi;
  const int e0 = swz * 128;
  const int wid = tid >> 6, lane = tid & 63;
  const int l16 = lane & 15, lk = lane >> 4;
  const int wr = wid * 32;
  const int lkoff = lk * 8;

  const int ea = e0 + wr + l16, eb = e0 + wr + 16 + l16;
  const size_t soff0 = (size_t)esrc_s[ea] * 256;
  const size_t soff1 = (size_t)esrc_s[eb] * 256;
  const size_t doff0 = (size_t)edst_s[ea] * 256 + 128;
  const size_t doff1 = (size_t)edst_s[eb] * 256 + 128;

  uint4 af[6][2][2];   // combined e fragments (src raw lands here first)
  uint4 dr[2][2][2];   // dst raw ring
  f32x4 acc[2][8];
#pragma unroll
  for (int mf = 0; mf < 2; ++mf)
#pragma unroll
    for (int nf = 0; nf < 8; ++nf) acc[mf][nf] = f32x4{0.f, 0.f, 0.f, 0.f};

#define TB(c) (Tall + (size_t)((c) >> 1) * ((size_t)NN * 256) + ((c) & 1) * 64 + lkoff)
#define LSRC(c) { const unsigned short* tb = TB(c); \
  af[c][0][0] = *reinterpret_cast<const uint4*>(tb + soff0); \
  af[c][0][1] = *reinterpret_cast<const uint4*>(tb + soff0 + 32); \
  af[c][1][0] = *reinterpret_cast<const uint4*>(tb + soff1); \
  af[c][1][1] = *reinterpret_cast<const uint4*>(tb + soff1 + 32); }
#define LDST(c) { const unsigned short* tb = TB(c); \
  dr[(c) & 1][0][0] = *reinterpret_cast<const uint4*>(tb + doff0); \
  dr[(c) & 1][0][1] = *reinterpret_cast<const uint4*>(tb + doff0 + 32); \
  dr[(c) & 1][1][0] = *reinterpret_cast<const uint4*>(tb + doff1); \
  dr[(c) & 1][1][1] = *reinterpret_cast<const uint4*>(tb + doff1 + 32); }
#define COMB(c) { \
  _Pragma("unroll") for (int mf = 0; mf < 2; ++mf) \
  _Pragma("unroll") for (int ks = 0; ks < 2; ++ks) { \
    uint4 s = af[c][mf][ks], d = dr[(c) & 1][mf][ks]; \
    uint4 r; r.x = combine2(s.x, d.x); r.y = combine2(s.y, d.y); \
    r.z = combine2(s.z, d.z); r.w = combine2(s.w, d.w); \
    af[c][mf][ks] = r; } }
#define PROCH(c, W) { \
  _Pragma("unroll") for (int ks = 0; ks < 2; ++ks) { \
    short8v a0 = *reinterpret_cast<short8v*>(&af[c][0][ks]); \
    short8v a1 = *reinterpret_cast<short8v*>(&af[c][1][ks]); \
    int kglob = (c) * 64 + ks * 32 + lkoff; \
    _Pragma("unroll") for (int nf = 0; nf < 8; ++nf) { \
      int col = nf * 16 + l16; \
      short8v b = *reinterpret_cast<const short8v*>(&W[(size_t)col * 384 + kglob]); \
      acc[0][nf] = MFMA_BF16(a0, b, acc[0][nf]); \
      acc[1][nf] = MFMA_BF16(a1, b, acc[1][nf]); } } }
#define EPI(B1, W2, B2, H) { \
  _Pragma("unroll") for (int mf = 0; mf < 2; ++mf) \
  _Pragma("unroll") for (int reg = 0; reg < 4; ++reg) { \
    float p0 = 0.f, p1 = 0.f; \
    _Pragma("unroll") for (int nf = 0; nf < 8; ++nf) { \
      int col = nf * 16 + l16; \
      float hv = fmaxf(acc[mf][nf][reg] + B1[col], 0.f); \
      p0 += hv * W2[col * 2]; p1 += hv * W2[col * 2 + 1]; } \
    _Pragma("unroll") for (int m = 1; m < 16; m <<= 1) { \
      p0 += __shfl_xor(p0, m); p1 += __shfl_xor(p1, m); } \
    if (l16 == 0) { \
      int orig = eorig_s[e0 + wr + mf * 16 + lk * 4 + reg]; \
      float l0 = p0 + B2[0], l1 = p1 + B2[1]; \
      float mx = fmaxf(l0, l1); \
      float lse = mx + __logf(__expf(l0 - mx) + __expf(l1 - mx)); \
      float2 o2 = make_float2(l0 - lse, l1 - lse); \
      *reinterpret_cast<float2*>(&out[(size_t)(H) * 2 * NE + (size_t)orig * 2]) = o2; } } }

  // issue ALL src gathers (24 loads) + first two dst chunks
  LSRC(0) LSRC(1) LSRC(2) LSRC(3) LSRC(4) LSRC(5)
  LDST(0) LDST(1)
  COMB(0) PROCH(0, rw1T) LDST(2)
  COMB(1) PROCH(1, rw1T) LDST(3)
  COMB(2) PROCH(2, rw1T) LDST(4)
  COMB(3) PROCH(3, rw1T) LDST(5)
  COMB(4) PROCH(4, rw1T)
  COMB(5) PROCH(5, rw1T)
  EPI(rb1, rw2, rb2, 0)

#pragma unroll
  for (int mf = 0; mf < 2; ++mf)
#pragma unroll
    for (int nf = 0; nf < 8; ++nf) acc[mf][nf] = f32x4{0.f, 0.f, 0.f, 0.f};

  __builtin_amdgcn_s_setprio(1);
  PROCH(0, cw1T) PROCH(1, cw1T) PROCH(2, cw1T)
  PROCH(3, cw1T) PROCH(4, cw1T) PROCH(5, cw1T)
  __builtin_amdgcn_s_setprio(0);
  EPI(cb1, cw2, cb2, 1)

#undef TB
#undef LSRC
#undef LDST
#undef COMB
#undef PROCH
#undef EPI
}

// ---------------- launch ----------------
extern "C" void kernel_launch(void* const* d_in, const int* in_sizes, int n_in,
                              void* d_out, int out_size, void* d_ws, size_t ws_size,
                              hipStream_t stream)
{
  const float* x       = (const float*)d_in[0];
  const int*   eidx    = (const int*)  d_in[1];
  const int*   xtext   = (const int*)  d_in[2];
  const float* imgf    = (const float*)d_in[3];
  const float* conv1_w = (const float*)d_in[4];
  const float* conv1_b = (const float*)d_in[5];
  const float* conv2_w = (const float*)d_in[6];
  const float* conv2_b = (const float*)d_in[7];
  const float* embed   = (const float*)d_in[8];
  const float* gwih    = (const float*)d_in[9];
  const float* gwhh    = (const float*)d_in[10];
  const float* gbih    = (const float*)d_in[11];
  const float* gbhh    = (const float*)d_in[12];
  const float* lpw     = (const float*)d_in[13];
  const float* lpb     = (const float*)d_in[14];
  const float* ltw     = (const float*)d_in[15];
  const float* ltb     = (const float*)d_in[16];
  const float* liw     = (const float*)d_in[17];
  const float* lib     = (const float*)d_in[18];
  const float* rw1     = (const float*)d_in[19];
  const float* rb1     = (const float*)d_in[20];
  const float* rw2     = (const float*)d_in[21];
  const float* rb2     = (const float*)d_in[22];
  const float* cw1     = (const float*)d_in[23];
  const float* cb1     = (const float*)d_in[24];
  const float* cw2     = (const float*)d_in[25];
  const float* cb2     = (const float*)d_in[26];
  float* out = (float*)d_out;

  char* w8 = (char*)d_ws;
  size_t off = 0;
  auto balloc = [&](size_t bytes) { void* p = w8 + off; off = (off + bytes + 255) & ~(size_t)255; return p; };
  float*          dinv   = (float*)balloc(NN * 4);
  int*            ideg   = (int*)balloc((NN + 1) * 4);
  int*            rowptr = (int*)balloc((NN + 1) * 4);
  int*            cursor = (int*)balloc((NN + 1) * 4);
  int*            esrc_s = (int*)balloc((size_t)NE * 4);
  int*            edst_s = (int*)balloc((size_t)NE * 4);
  int*            eorig_s= (int*)balloc((size_t)NE * 4);
  unsigned int*   xwsB   = (unsigned int*)balloc((size_t)NN * 64 * 4);
  unsigned int*   nodeB  = (unsigned int*)balloc((size_t)NN * 64 * 4);
  unsigned short* txtB   = (unsigned short*)balloc((size_t)NN * HH * 2);
  unsigned short* imgB   = (unsigned short*)balloc((size_t)NN * 256 * 2);
  unsigned short* Tall   = (unsigned short*)balloc((size_t)3 * NN * 256 * 2);
  unsigned short* wihB   = (unsigned short*)balloc(384 * 64 * 2);
  unsigned short* whhB   = (unsigned short*)balloc(384 * 128 * 2);
  unsigned short* rw1T   = (unsigned short*)balloc(384 * 128 * 2);
  unsigned short* cw1T   = (unsigned short*)balloc(384 * 128 * 2);
  unsigned short* conv2T = (unsigned short*)balloc(128 * 128 * 2);
  unsigned short* TposW  = (unsigned short*)balloc(256 * 128 * 2);
  unsigned short* TtxtW  = (unsigned short*)balloc(256 * 128 * 2);
  unsigned short* TimgW  = (unsigned short*)balloc(256 * 256 * 2);
  float*          bcomb  = (float*)balloc(768 * 4);
  float*          brz    = (float*)balloc(256 * 4);
  float*          binv   = (float*)balloc(128 * 4);
  float*          bhnv   = (float*)balloc(128 * 4);

  dim3 b256(256);
  auto cdiv = [](int a, int b) { return (a + b - 1) / b; };
  const int MB64 = cdiv(NN, 64); // 313

  // ---- fused weight prep + img cast ----
  prep_k<<<cdiv(320768, 256), b256, 0, stream>>>(
      gwih, gwhh, rw1, cw1, conv2_w, lpw, ltw, liw, lpb, ltb, lib, gbih, gbhh,
      wihB, whhB, rw1T, cw1T, conv2T, TposW, TtxtW, TimgW, bcomb, brz, binv, bhnv);
  cvtf2_k<<<cdiv(NN * 128, 256), b256, 0, stream>>>(imgf, (unsigned int*)imgB, NN * 128);

  // ---- dst-sorted CSR + dinv ----
  fill_zero_k<<<cdiv(NN + 1, 256), b256, 0, stream>>>((float*)ideg, NN + 1);
  histo_k<<<cdiv(NE, 256), b256, 0, stream>>>(eidx, ideg);
  scan_k<<<1, b256, 0, stream>>>(ideg, rowptr);
  dinv_csr_k<<<cdiv(NN, 256), b256, 0, stream>>>(rowptr, dinv);
  hipMemcpyAsync(cursor, rowptr, (NN + 1) * sizeof(int), hipMemcpyDeviceToDevice, stream);
  scatter_k<<<cdiv(NE, 256), b256, 0, stream>>>(eidx, cursor, esrc_s, edst_s, eorig_s);

  // ---- GCN layer 1: prescaled bf16 rows -> CSR sum ----
  xw1_k<<<cdiv(NN * 64, 256), b256, 0, stream>>>(x, conv1_w, dinv, xwsB);
  gcn_csr_k<<<cdiv(NN, 4), b256, 0, stream>>>(rowptr, esrc_s, xwsB, dinv, conv1_b, nodeB);

  // ---- GCN layer 2: MFMA (bf16 out, row-prescaled) -> CSR sum ----
  gemm_mfma_k<128, 128, true, false, true><<<dim3(MB64, 1), b256, 0, stream>>>(
      (const unsigned short*)nodeB, conv2T, nullptr, dinv, xwsB, NN);
  gcn_csr_k<<<cdiv(NN, 4), b256, 0, stream>>>(rowptr, esrc_s, xwsB, dinv, conv2_b, nodeB);

  // ---- GRU -> txt bf16 ----
  gru_fused_k<<<NN / 32, b256, 0, stream>>>(xtext, embed, wihB, whhB, brz, binv, bhnv, txtB);

  // ---- node tables (bf16, combined src|dst cols) ----
  gemm_mfma_k<128, 256, true, true, false><<<dim3(MB64, 2), b256, 0, stream>>>(
      (const unsigned short*)nodeB, TposW, bcomb, nullptr, Tall, NN);
  gemm_mfma_k<128, 256, true, true, false><<<dim3(MB64, 2), b256, 0, stream>>>(
      txtB, TtxtW, bcomb + 256, nullptr, Tall + (size_t)NN * 256, NN);
  gemm_mfma_k<256, 256, true, true, false><<<dim3(MB64, 2), b256, 0, stream>>>(
      imgB, TimgW, bcomb + 512, nullptr, Tall + (size_t)2 * NN * 256, NN);

  // ---- fused edge heads + log_softmax (dst-sorted order, XCD-swizzled) ----
  edge_mfma_k<<<NE / 128, b256, 0, stream>>>(esrc_s, edst_s, eorig_s, Tall,
                                             rw1T, rb1, rw2, rb2, cw1T, cb1, cw2, cb2, out);
}

// Round 10
// 711.536 us; speedup vs baseline: 1.4036x; 1.1634x over previous
//
#include <hip/hip_runtime.h>
#include <hip/hip_bf16.h>

#define NN 20000
#define NE 320000
#define LL 16
#define TT 64
#define HH 128

typedef __attribute__((ext_vector_type(8))) short short8v;
typedef __attribute__((ext_vector_type(4))) float f32x4;
#define MFMA_BF16(a,b,c) __builtin_amdgcn_mfma_f32_16x16x32_bf16(a,b,c,0,0,0)

__device__ inline unsigned short f32_to_bf16(float v) {
  unsigned int b = __float_as_uint(v);
  b += 0x7fffu + ((b >> 16) & 1u);
  return (unsigned short)(b >> 16);
}
__device__ inline float bf16_to_f32(unsigned short u) {
  return __uint_as_float(((unsigned int)u) << 16);
}
__device__ inline float fast_sigmoid(float x) {
  return __builtin_amdgcn_rcpf(1.f + __expf(-x));
}
__device__ inline float fast_tanh(float x) {
  float e = __expf(2.f * x);
  return 1.f - 2.f * __builtin_amdgcn_rcpf(e + 1.f);
}
__device__ inline unsigned int cvt_pk_bf16(float lo, float hi) {
  unsigned int r;
  asm("v_cvt_pk_bf16_f32 %0, %1, %2" : "=v"(r) : "v"(lo), "v"(hi));
  return r;
}
__device__ inline unsigned int combine2(unsigned int us, unsigned int ud) {
  float sl = __uint_as_float(us << 16);
  float sh = __uint_as_float(us & 0xffff0000u);
  float dl = __uint_as_float(ud << 16);
  float dh = __uint_as_float(ud & 0xffff0000u);
  return cvt_pk_bf16(fmaxf(sl + dl, 0.f), fmaxf(sh + dh, 0.f));
}

// ---------------- fused prep ----------------
__global__ void prep_k(
    const float* __restrict__ gwih, const float* __restrict__ gwhh,
    const float* __restrict__ rw1, const float* __restrict__ cw1,
    const float* __restrict__ conv2w,
    const float* __restrict__ lpw, const float* __restrict__ ltw, const float* __restrict__ liw,
    const float* __restrict__ lpb, const float* __restrict__ ltb, const float* __restrict__ lib,
    const float* __restrict__ gbih, const float* __restrict__ gbhh,
    unsigned short* __restrict__ wihB, unsigned short* __restrict__ whhB,
    unsigned short* __restrict__ rw1T, unsigned short* __restrict__ cw1T,
    unsigned short* __restrict__ conv2T,
    unsigned short* __restrict__ TposW, unsigned short* __restrict__ TtxtW,
    unsigned short* __restrict__ TimgW,
    float* __restrict__ bcomb, float* __restrict__ brz,
    float* __restrict__ binv, float* __restrict__ bhnv)
{
  int i = blockIdx.x * 256 + threadIdx.x;
  if (i < 24576) { wihB[i] = f32_to_bf16(gwih[i]); return; } i -= 24576;
  if (i < 49152) { whhB[i] = f32_to_bf16(gwhh[i]); return; } i -= 49152;
  if (i < 49152) { int c = i / 384, r = i - c * 384; rw1T[i] = f32_to_bf16(rw1[r * 128 + c]); return; } i -= 49152;
  if (i < 49152) { int c = i / 384, r = i - c * 384; cw1T[i] = f32_to_bf16(cw1[r * 128 + c]); return; } i -= 49152;
  if (i < 16384) { int c = i / 128, r = i - c * 128; conv2T[i] = f32_to_bf16(conv2w[r * 128 + c]); return; } i -= 16384;
  if (i < 32768) { int col = i / 128, k = i - col * 128;
    float v = (col < 128) ? lpw[k * 128 + col] : lpw[(128 + k) * 128 + (col - 128)];
    TposW[i] = f32_to_bf16(v); return; } i -= 32768;
  if (i < 32768) { int col = i / 128, k = i - col * 128;
    float v = (col < 128) ? ltw[k * 128 + col] : ltw[(128 + k) * 128 + (col - 128)];
    TtxtW[i] = f32_to_bf16(v); return; } i -= 32768;
  if (i < 65536) { int col = i / 256, k = i - col * 256;
    float v = (col < 128) ? liw[k * 128 + col] : liw[(256 + k) * 128 + (col - 128)];
    TimgW[i] = f32_to_bf16(v); return; } i -= 65536;
  if (i < 768) { int t = i >> 8, j = i & 255;
    const float* b = t == 0 ? lpb : t == 1 ? ltb : lib;
    bcomb[i] = (j < 128) ? 0.f : b[j - 128]; return; } i -= 768;
  if (i < 512) {
    if (i < 256) brz[i] = gbih[i] + gbhh[i];
    else if (i < 384) binv[i - 256] = gbih[i];
    else bhnv[i - 384] = gbhh[i - 128];
  }
}

__global__ void cvtf2_k(const float* __restrict__ in, unsigned int* __restrict__ out, int n2) {
  int i = blockIdx.x * 256 + threadIdx.x;
  if (i < n2) {
    float2 v = reinterpret_cast<const float2*>(in)[i];
    out[i] = cvt_pk_bf16(v.x, v.y);
  }
}

// ---------------- CSR build ----------------
__global__ void fill_zero_k(float* __restrict__ p, int n) {
  int i = blockIdx.x * 256 + threadIdx.x;
  if (i < n) p[i] = 0.f;
}

__global__ void histo_k(const int* __restrict__ eidx, int* __restrict__ ideg) {
  int e = blockIdx.x * 256 + threadIdx.x;
  if (e < NE) atomicAdd(&ideg[eidx[NE + e]], 1);
}

__global__ void scan_k(const int* __restrict__ ideg, int* __restrict__ rowptr) {
  __shared__ int sh[256];
  __shared__ int carry;
  const int tid = threadIdx.x;
  if (tid == 0) carry = 0;
  __syncthreads();
  for (int base = 0; base < NN; base += 256) {
    int v = (base + tid < NN) ? ideg[base + tid] : 0;
    sh[tid] = v;
    __syncthreads();
#pragma unroll
    for (int off = 1; off < 256; off <<= 1) {
      int t = (tid >= off) ? sh[tid - off] : 0;
      __syncthreads();
      sh[tid] += t;
      __syncthreads();
    }
    if (base + tid < NN) rowptr[base + tid] = carry + sh[tid] - v;
    __syncthreads();
    if (tid == 255) carry += sh[255];
    __syncthreads();
  }
  if (tid == 0) rowptr[NN] = carry;
}

__global__ void dinv_csr_k(const int* __restrict__ rowptr, float* __restrict__ dinv) {
  int i = blockIdx.x * 256 + threadIdx.x;
  if (i < NN) dinv[i] = rsqrtf((float)(rowptr[i + 1] - rowptr[i]) + 1.f);
}

__global__ void scatter_k(const int* __restrict__ eidx, int* __restrict__ cursor,
                          int* __restrict__ esrc_s, int* __restrict__ edst_s,
                          int* __restrict__ eorig_s) {
  int e = blockIdx.x * 256 + threadIdx.x;
  if (e >= NE) return;
  int s = eidx[e], d = eidx[NE + e];
  int pos = atomicAdd(&cursor[d], 1);
  esrc_s[pos] = s;
  edst_s[pos] = d;
  eorig_s[pos] = e;
}

// ---------------- conv1: xws1 = (x @ w1) * dinv[row], bf16 ----------------
__global__ void xw1_k(const float* __restrict__ x, const float* __restrict__ w,
                      const float* __restrict__ dinv, unsigned int* __restrict__ xws) {
  int i = blockIdx.x * 256 + threadIdx.x;
  if (i >= NN * 64) return;
  int n = i >> 6, c2 = (i & 63) * 2;
  float a0 = 0.f, a1 = 0.f;
#pragma unroll
  for (int k = 0; k < 8; ++k) {
    float xv = x[n * 8 + k];
    a0 += xv * w[k * 128 + c2];
    a1 += xv * w[k * 128 + c2 + 1];
  }
  float dn = dinv[n];
  xws[i] = cvt_pk_bf16(a0 * dn, a1 * dn);
}

// ---------------- atomic-free GCN aggregate over prescaled bf16 rows -----------
__global__ __launch_bounds__(256) void gcn_csr_k(
    const int* __restrict__ rowptr, const int* __restrict__ esrc_s,
    const unsigned int* __restrict__ xws, const float* __restrict__ dinv,
    const float* __restrict__ bias, unsigned int* __restrict__ outB)
{
  int node = blockIdx.x * 4 + (threadIdx.x >> 6);
  int lane = threadIdx.x & 63;
  if (node >= NN) return;
  float dd = dinv[node];
  int beg = rowptr[node], end = rowptr[node + 1];
  float a0 = 0.f, a1 = 0.f;
  int i = beg;
  for (; i + 1 < end; i += 2) {
    int s0 = esrc_s[i], s1 = esrc_s[i + 1];
    unsigned int u0 = xws[s0 * 64 + lane];
    unsigned int u1 = xws[s1 * 64 + lane];
    a0 += __uint_as_float(u0 << 16) + __uint_as_float(u1 << 16);
    a1 += __uint_as_float(u0 & 0xffff0000u) + __uint_as_float(u1 & 0xffff0000u);
  }
  if (i < end) {
    unsigned int u = xws[esrc_s[i] * 64 + lane];
    a0 += __uint_as_float(u << 16);
    a1 += __uint_as_float(u & 0xffff0000u);
  }
  unsigned int un = xws[node * 64 + lane];
  a0 += __uint_as_float(un << 16);
  a1 += __uint_as_float(un & 0xffff0000u);
  a0 = fmaxf(a0 * dd + bias[lane * 2], 0.f);
  a1 = fmaxf(a1 * dd + bias[lane * 2 + 1], 0.f);
  outB[node * 64 + lane] = cvt_pk_bf16(a0, a1);
}

// ---------------- direct-fragment MFMA GEMM (BM=128, round-6 proven) ---------
template<int KDIM, int NCOLS, bool OUTBF16, bool ADDBIAS, bool SCALEROW>
__global__ __launch_bounds__(256) void gemm_mfma_k(
    const unsigned short* __restrict__ A, const unsigned short* __restrict__ WT,
    const float* __restrict__ bias, const float* __restrict__ rowscale,
    void* __restrict__ Cv, int M)
{
  const int tid = threadIdx.x;
  const int wid = tid >> 6, lane = tid & 63;
  const int l16 = lane & 15, lk = lane >> 4;
  const int bm = blockIdx.x * 128, bn = blockIdx.y * 128;
  const int wr = wid * 32;

  int row[2];
#pragma unroll
  for (int mf = 0; mf < 2; ++mf) {
    int r = bm + wr + mf * 16 + l16;
    row[mf] = r < M ? r : M - 1;
  }
  f32x4 acc[2][8];
#pragma unroll
  for (int mf = 0; mf < 2; ++mf)
#pragma unroll
    for (int nf = 0; nf < 8; ++nf) acc[mf][nf] = f32x4{0.f, 0.f, 0.f, 0.f};

#pragma unroll
  for (int kc = 0; kc < KDIM / 32; ++kc) {
    short8v a[2];
#pragma unroll
    for (int mf = 0; mf < 2; ++mf)
      a[mf] = *reinterpret_cast<const short8v*>(&A[(size_t)row[mf] * KDIM + kc * 32 + lk * 8]);
#pragma unroll
    for (int nf = 0; nf < 8; ++nf) {
      int col = bn + nf * 16 + l16;
      short8v b = *reinterpret_cast<const short8v*>(&WT[(size_t)col * KDIM + kc * 32 + lk * 8]);
      acc[0][nf] = MFMA_BF16(a[0], b, acc[0][nf]);
      acc[1][nf] = MFMA_BF16(a[1], b, acc[1][nf]);
    }
  }
#pragma unroll
  for (int mf = 0; mf < 2; ++mf)
#pragma unroll
    for (int nf = 0; nf < 8; ++nf) {
      int col = bn + nf * 16 + l16;
      float bb = ADDBIAS ? bias[col] : 0.f;
#pragma unroll
      for (int reg = 0; reg < 4; ++reg) {
        int r = bm + wr + mf * 16 + lk * 4 + reg;
        if (r < M) {
          float v = acc[mf][nf][reg] + bb;
          if (SCALEROW) v *= rowscale[r];
          if (OUTBF16) ((unsigned short*)Cv)[(size_t)r * NCOLS + col] = f32_to_bf16(v);
          else         ((float*)Cv)[(size_t)r * NCOLS + col] = v;
        }
      }
    }
}

// ---------------- fused persistent GRU (32 nodes/block, weights in registers) --
__global__ __launch_bounds__(256, 2) void gru_fused_k(
    const int* __restrict__ xtext, const float* __restrict__ embed,
    const unsigned short* __restrict__ wihB, const unsigned short* __restrict__ whhB,
    const float* __restrict__ brz, const float* __restrict__ binv, const float* __restrict__ bhnv,
    unsigned short* __restrict__ txt)
{
  __shared__ unsigned char hs[2][32 * 256];
  __shared__ unsigned char xs[32 * 128];
  const int tid = threadIdx.x;
  const int n0 = blockIdx.x * 32;
  const int wid = tid >> 6, lane = tid & 63;
  const int l16 = lane & 15, lk = lane >> 4;

  for (int i = tid; i < 32 * 256 / 4; i += 256) ((unsigned int*)hs[0])[i] = 0u;

  short8v wR[2][2], wZ[2][2], wN[2][2];
  short8v uR[2][4], uZ[2][4], uN[2][4];
  float bRr[2], bZr[2], bIr[2], bHr[2];
#pragma unroll
  for (int cf = 0; cf < 2; ++cf) {
    int col = wid * 32 + cf * 16 + l16;
#pragma unroll
    for (int ks = 0; ks < 2; ++ks) {
      wR[cf][ks] = *reinterpret_cast<const short8v*>(&wihB[(col      ) * 64 + ks * 32 + lk * 8]);
      wZ[cf][ks] = *reinterpret_cast<const short8v*>(&wihB[(col + 128) * 64 + ks * 32 + lk * 8]);
      wN[cf][ks] = *reinterpret_cast<const short8v*>(&wihB[(col + 256) * 64 + ks * 32 + lk * 8]);
    }
#pragma unroll
    for (int ks = 0; ks < 4; ++ks) {
      uR[cf][ks] = *reinterpret_cast<const short8v*>(&whhB[(col      ) * 128 + ks * 32 + lk * 8]);
      uZ[cf][ks] = *reinterpret_cast<const short8v*>(&whhB[(col + 128) * 128 + ks * 32 + lk * 8]);
      uN[cf][ks] = *reinterpret_cast<const short8v*>(&whhB[(col + 256) * 128 + ks * 32 + lk * 8]);
    }
    bRr[cf] = brz[col]; bZr[cf] = brz[128 + col];
    bIr[cf] = binv[col]; bHr[cf] = bhnv[col];
  }

  f32x4 txtacc[2][2];
#pragma unroll
  for (int mf = 0; mf < 2; ++mf)
#pragma unroll
    for (int cf = 0; cf < 2; ++cf) txtacc[mf][cf] = f32x4{0.f, 0.f, 0.f, 0.f};

  int cur = 0;
  for (int t = 0; t < LL; ++t) {
    __syncthreads();
    {
      const int k4 = tid & 15, r0 = tid >> 4;
#pragma unroll
      for (int rep = 0; rep < 2; ++rep) {
        int row = r0 + rep * 16;
        int n = n0 + row; if (n >= NN) n = NN - 1;
        int tok = xtext[n * LL + t];
        float4 v = *reinterpret_cast<const float4*>(&embed[(size_t)tok * TT + k4 * 4]);
        ushort4 w;
        w.x = f32_to_bf16(v.x); w.y = f32_to_bf16(v.y);
        w.z = f32_to_bf16(v.z); w.w = f32_to_bf16(v.w);
        *reinterpret_cast<ushort4*>(&xs[row * 128 + ((k4 * 8) ^ ((row & 7) << 4))]) = w;
      }
    }
    __syncthreads();

#pragma unroll
    for (int mf = 0; mf < 2; ++mf) {
      const int arow = mf * 16 + l16;
      const int asw = (arow & 7) << 4;
      short8v ax[2], ah[4];
#pragma unroll
      for (int ks = 0; ks < 2; ++ks)
        ax[ks] = *reinterpret_cast<const short8v*>(&xs[arow * 128 + ((ks * 64 + lk * 16) ^ asw)]);
#pragma unroll
      for (int ks = 0; ks < 4; ++ks)
        ah[ks] = *reinterpret_cast<const short8v*>(&hs[cur][arow * 256 + ((ks * 64 + lk * 16) ^ asw)]);

      f32x4 aR[2], aZ[2], aI[2], aHn[2];
#pragma unroll
      for (int cf = 0; cf < 2; ++cf) {
        aR[cf] = f32x4{0.f, 0.f, 0.f, 0.f}; aZ[cf] = f32x4{0.f, 0.f, 0.f, 0.f};
        aI[cf] = f32x4{0.f, 0.f, 0.f, 0.f}; aHn[cf] = f32x4{0.f, 0.f, 0.f, 0.f};
#pragma unroll
        for (int ks = 0; ks < 2; ++ks) {
          aR[cf] = MFMA_BF16(ax[ks], wR[cf][ks], aR[cf]);
          aZ[cf] = MFMA_BF16(ax[ks], wZ[cf][ks], aZ[cf]);
          aI[cf] = MFMA_BF16(ax[ks], wN[cf][ks], aI[cf]);
        }
#pragma unroll
        for (int ks = 0; ks < 4; ++ks) {
          aR[cf]  = MFMA_BF16(ah[ks], uR[cf][ks], aR[cf]);
          aZ[cf]  = MFMA_BF16(ah[ks], uZ[cf][ks], aZ[cf]);
          aHn[cf] = MFMA_BF16(ah[ks], uN[cf][ks], aHn[cf]);
        }
      }

#pragma unroll
      for (int cf = 0; cf < 2; ++cf) {
        const int j = wid * 32 + cf * 16 + l16;
#pragma unroll
        for (int reg = 0; reg < 4; ++reg) {
          const int row = mf * 16 + lk * 4 + reg;
          const int byte = row * 256 + ((j * 2) ^ ((row & 7) << 4));
          float hold = bf16_to_f32(*reinterpret_cast<unsigned short*>(&hs[cur][byte]));
          float rg = fast_sigmoid(aR[cf][reg] + bRr[cf]);
          float zg = fast_sigmoid(aZ[cf][reg] + bZr[cf]);
          float ng = fast_tanh(aI[cf][reg] + bIr[cf] + rg * (aHn[cf][reg] + bHr[cf]));
          float h2 = (1.f - zg) * ng + zg * hold;
          txtacc[mf][cf][reg] += h2;
          *reinterpret_cast<unsigned short*>(&hs[cur ^ 1][byte]) = f32_to_bf16(h2);
        }
      }
    }
    cur ^= 1;
  }

#pragma unroll
  for (int mf = 0; mf < 2; ++mf)
#pragma unroll
    for (int cf = 0; cf < 2; ++cf) {
      const int j = wid * 32 + cf * 16 + l16;
#pragma unroll
      for (int reg = 0; reg < 4; ++reg) {
        const int row = mf * 16 + lk * 4 + reg;
        const int n = n0 + row;
        if (n < NN) txt[(size_t)n * HH + j] = f32_to_bf16(txtacc[mf][cf][reg]);
      }
    }
}

// ---------------- fused edge heads: weights in LDS (lgkmcnt), gathers in vmcnt --
// Block: 128 edges, 4 waves x 32 edges. Weights for the active head staged into
// 96KB LDS (12 slices of [128 cols][32 k], conflict-free for ds_read_b128), so
// MFMA B-frag consumption no longer drains the gather queue (vmcnt stays
// gathers-only -> src burst + dst ring-2 actually pipeline).
__global__ __launch_bounds__(256, 1) void edge_mfma_k(
    const int* __restrict__ esrc_s, const int* __restrict__ edst_s,
    const int* __restrict__ eorig_s,
    const unsigned short* __restrict__ Tall,
    const unsigned short* __restrict__ rw1T, const float* __restrict__ rb1,
    const float* __restrict__ rw2, const float* __restrict__ rb2,
    const unsigned short* __restrict__ cw1T, const float* __restrict__ cb1,
    const float* __restrict__ cw2, const float* __restrict__ cb2,
    float* __restrict__ out)
{
  __shared__ __align__(16) unsigned char wlds[98304]; // 12 slices x 8KB
  const int tid = threadIdx.x;
  const int bid = blockIdx.x;
  const int xcd = bid & 7, bi = bid >> 3;
  const int swz = (xcd < 4 ? xcd * 313 : 4 * 313 + (xcd - 4) * 312) + bi;
  const int e0 = swz * 128;
  const int wid = tid >> 6, lane = tid & 63;
  const int l16 = lane & 15, lk = lane >> 4;
  const int wr = wid * 32;
  const int lkoff = lk * 8;

  const int ea = e0 + wr + l16, eb = e0 + wr + 16 + l16;
  const size_t soff0 = (size_t)esrc_s[ea] * 256;
  const size_t soff1 = (size_t)esrc_s[eb] * 256;
  const size_t doff0 = (size_t)edst_s[ea] * 256 + 128;
  const size_t doff1 = (size_t)edst_s[eb] * 256 + 128;

  uint4 af[6][2][2];   // combined e fragments (src raw lands here first)
  uint4 dr[2][2][2];   // dst raw ring
  f32x4 acc[2][8];
#pragma unroll
  for (int mf = 0; mf < 2; ++mf)
#pragma unroll
    for (int nf = 0; nf < 8; ++nf) acc[mf][nf] = f32x4{0.f, 0.f, 0.f, 0.f};

#define TB(c) (Tall + (size_t)((c) >> 1) * ((size_t)NN * 256) + ((c) & 1) * 64 + lkoff)
#define LSRC(c) { const unsigned short* tb = TB(c); \
  af[c][0][0] = *reinterpret_cast<const uint4*>(tb + soff0); \
  af[c][0][1] = *reinterpret_cast<const uint4*>(tb + soff0 + 32); \
  af[c][1][0] = *reinterpret_cast<const uint4*>(tb + soff1); \
  af[c][1][1] = *reinterpret_cast<const uint4*>(tb + soff1 + 32); }
#define LDST(c) { const unsigned short* tb = TB(c); \
  dr[(c) & 1][0][0] = *reinterpret_cast<const uint4*>(tb + doff0); \
  dr[(c) & 1][0][1] = *reinterpret_cast<const uint4*>(tb + doff0 + 32); \
  dr[(c) & 1][1][0] = *reinterpret_cast<const uint4*>(tb + doff1); \
  dr[(c) & 1][1][1] = *reinterpret_cast<const uint4*>(tb + doff1 + 32); }
#define COMB(c) { \
  _Pragma("unroll") for (int mf = 0; mf < 2; ++mf) \
  _Pragma("unroll") for (int ks = 0; ks < 2; ++ks) { \
    uint4 s = af[c][mf][ks], d = dr[(c) & 1][mf][ks]; \
    uint4 r; r.x = combine2(s.x, d.x); r.y = combine2(s.y, d.y); \
    r.z = combine2(s.z, d.z); r.w = combine2(s.w, d.w); \
    af[c][mf][ks] = r; } }
// stage 3 slices (8KB each) of W for this wave: slice s = (c,ks),
// layout [col][32k] (col stride 64B) -> ds_read_b128 is conflict-free.
#define STAGEW(W) { \
  _Pragma("unroll") for (int s2 = 0; s2 < 3; ++s2) { \
    int s = wid * 3 + s2; \
    int kg = (s >> 1) * 64 + (s & 1) * 32; \
    _Pragma("unroll") for (int i = 0; i < 8; ++i) { \
      int col = i * 16 + (lane >> 2); \
      uint4 t = *reinterpret_cast<const uint4*>(&W[(size_t)col * 384 + kg + (lane & 3) * 8]); \
      *reinterpret_cast<uint4*>(&wlds[s * 8192 + i * 1024 + lane * 16]) = t; \
    } } }
#define PROCHL(c) { \
  _Pragma("unroll") for (int ks = 0; ks < 2; ++ks) { \
    short8v a0 = *reinterpret_cast<short8v*>(&af[c][0][ks]); \
    short8v a1 = *reinterpret_cast<short8v*>(&af[c][1][ks]); \
    const unsigned char* wb = &wlds[((c) * 2 + ks) * 8192 + lk * 16]; \
    _Pragma("unroll") for (int nf = 0; nf < 8; ++nf) { \
      short8v b = *reinterpret_cast<const short8v*>(wb + (nf * 16 + l16) * 64); \
      acc[0][nf] = MFMA_BF16(a0, b, acc[0][nf]); \
      acc[1][nf] = MFMA_BF16(a1, b, acc[1][nf]); } } }
#define EPI(B1, W2, B2, H) { \
  _Pragma("unroll") for (int mf = 0; mf < 2; ++mf) \
  _Pragma("unroll") for (int reg = 0; reg < 4; ++reg) { \
    float p0 = 0.f, p1 = 0.f; \
    _Pragma("unroll") for (int nf = 0; nf < 8; ++nf) { \
      int col = nf * 16 + l16; \
      float hv = fmaxf(acc[mf][nf][reg] + B1[col], 0.f); \
      p0 += hv * W2[col * 2]; p1 += hv * W2[col * 2 + 1]; } \
    _Pragma("unroll") for (int m = 1; m < 16; m <<= 1) { \
      p0 += __shfl_xor(p0, m); p1 += __shfl_xor(p1, m); } \
    if (l16 == 0) { \
      int orig = eorig_s[e0 + wr + mf * 16 + lk * 4 + reg]; \
      float l0 = p0 + B2[0], l1 = p1 + B2[1]; \
      float mx = fmaxf(l0, l1); \
      float lse = mx + __logf(__expf(l0 - mx) + __expf(l1 - mx)); \
      float2 o2 = make_float2(l0 - lse, l1 - lse); \
      *reinterpret_cast<float2*>(&out[(size_t)(H) * 2 * NE + (size_t)orig * 2]) = o2; } } }

  // issue all src gathers + dst ring prologue, then stage head0 weights
  LSRC(0) LSRC(1) LSRC(2) LSRC(3) LSRC(4) LSRC(5)
  LDST(0) LDST(1)
  STAGEW(rw1T)
  __syncthreads();

  // head 0: MFMAs read W from LDS; vmcnt queue holds only dst-ring gathers
  COMB(0) PROCHL(0) LDST(2)
  COMB(1) PROCHL(1) LDST(3)
  COMB(2) PROCHL(2) LDST(4)
  COMB(3) PROCHL(3) LDST(5)
  COMB(4) PROCHL(4)
  COMB(5) PROCHL(5)
  EPI(rb1, rw2, rb2, 0)

  __syncthreads();
  STAGEW(cw1T)
  __syncthreads();

  // head 1: pure LDS + register compute
#pragma unroll
  for (int mf = 0; mf < 2; ++mf)
#pragma unroll
    for (int nf = 0; nf < 8; ++nf) acc[mf][nf] = f32x4{0.f, 0.f, 0.f, 0.f};
  PROCHL(0) PROCHL(1) PROCHL(2) PROCHL(3) PROCHL(4) PROCHL(5)
  EPI(cb1, cw2, cb2, 1)

#undef TB
#undef LSRC
#undef LDST
#undef COMB
#undef STAGEW
#undef PROCHL
#undef EPI
}

// ---------------- launch ----------------
extern "C" void kernel_launch(void* const* d_in, const int* in_sizes, int n_in,
                              void* d_out, int out_size, void* d_ws, size_t ws_size,
                              hipStream_t stream)
{
  const float* x       = (const float*)d_in[0];
  const int*   eidx    = (const int*)  d_in[1];
  const int*   xtext   = (const int*)  d_in[2];
  const float* imgf    = (const float*)d_in[3];
  const float* conv1_w = (const float*)d_in[4];
  const float* conv1_b = (const float*)d_in[5];
  const float* conv2_w = (const float*)d_in[6];
  const float* conv2_b = (const float*)d_in[7];
  const float* embed   = (const float*)d_in[8];
  const float* gwih    = (const float*)d_in[9];
  const float* gwhh    = (const float*)d_in[10];
  const float* gbih    = (const float*)d_in[11];
  const float* gbhh    = (const float*)d_in[12];
  const float* lpw     = (const float*)d_in[13];
  const float* lpb     = (const float*)d_in[14];
  const float* ltw     = (const float*)d_in[15];
  const float* ltb     = (const float*)d_in[16];
  const float* liw     = (const float*)d_in[17];
  const float* lib     = (const float*)d_in[18];
  const float* rw1     = (const float*)d_in[19];
  const float* rb1     = (const float*)d_in[20];
  const float* rw2     = (const float*)d_in[21];
  const float* rb2     = (const float*)d_in[22];
  const float* cw1     = (const float*)d_in[23];
  const float* cb1     = (const float*)d_in[24];
  const float* cw2     = (const float*)d_in[25];
  const float* cb2     = (const float*)d_in[26];
  float* out = (float*)d_out;

  char* w8 = (char*)d_ws;
  size_t off = 0;
  auto balloc = [&](size_t bytes) { void* p = w8 + off; off = (off + bytes + 255) & ~(size_t)255; return p; };
  float*          dinv   = (float*)balloc(NN * 4);
  int*            ideg   = (int*)balloc((NN + 1) * 4);
  int*            rowptr = (int*)balloc((NN + 1) * 4);
  int*            cursor = (int*)balloc((NN + 1) * 4);
  int*            esrc_s = (int*)balloc((size_t)NE * 4);
  int*            edst_s = (int*)balloc((size_t)NE * 4);
  int*            eorig_s= (int*)balloc((size_t)NE * 4);
  unsigned int*   xwsB   = (unsigned int*)balloc((size_t)NN * 64 * 4);
  unsigned int*   nodeB  = (unsigned int*)balloc((size_t)NN * 64 * 4);
  unsigned short* txtB   = (unsigned short*)balloc((size_t)NN * HH * 2);
  unsigned short* imgB   = (unsigned short*)balloc((size_t)NN * 256 * 2);
  unsigned short* Tall   = (unsigned short*)balloc((size_t)3 * NN * 256 * 2);
  unsigned short* wihB   = (unsigned short*)balloc(384 * 64 * 2);
  unsigned short* whhB   = (unsigned short*)balloc(384 * 128 * 2);
  unsigned short* rw1T   = (unsigned short*)balloc(384 * 128 * 2);
  unsigned short* cw1T   = (unsigned short*)balloc(384 * 128 * 2);
  unsigned short* conv2T = (unsigned short*)balloc(128 * 128 * 2);
  unsigned short* TposW  = (unsigned short*)balloc(256 * 128 * 2);
  unsigned short* TtxtW  = (unsigned short*)balloc(256 * 128 * 2);
  unsigned short* TimgW  = (unsigned short*)balloc(256 * 256 * 2);
  float*          bcomb  = (float*)balloc(768 * 4);
  float*          brz    = (float*)balloc(256 * 4);
  float*          binv   = (float*)balloc(128 * 4);
  float*          bhnv   = (float*)balloc(128 * 4);

  dim3 b256(256);
  auto cdiv = [](int a, int b) { return (a + b - 1) / b; };
  const int MB = cdiv(NN, 128); // 157

  // ---- fused weight prep + img cast ----
  prep_k<<<cdiv(320768, 256), b256, 0, stream>>>(
      gwih, gwhh, rw1, cw1, conv2_w, lpw, ltw, liw, lpb, ltb, lib, gbih, gbhh,
      wihB, whhB, rw1T, cw1T, conv2T, TposW, TtxtW, TimgW, bcomb, brz, binv, bhnv);
  cvtf2_k<<<cdiv(NN * 128, 256), b256, 0, stream>>>(imgf, (unsigned int*)imgB, NN * 128);

  // ---- dst-sorted CSR + dinv ----
  fill_zero_k<<<cdiv(NN + 1, 256), b256, 0, stream>>>((float*)ideg, NN + 1);
  histo_k<<<cdiv(NE, 256), b256, 0, stream>>>(eidx, ideg);
  scan_k<<<1, b256, 0, stream>>>(ideg, rowptr);
  dinv_csr_k<<<cdiv(NN, 256), b256, 0, stream>>>(rowptr, dinv);
  hipMemcpyAsync(cursor, rowptr, (NN + 1) * sizeof(int), hipMemcpyDeviceToDevice, stream);
  scatter_k<<<cdiv(NE, 256), b256, 0, stream>>>(eidx, cursor, esrc_s, edst_s, eorig_s);

  // ---- GCN layer 1: prescaled bf16 rows -> CSR sum ----
  xw1_k<<<cdiv(NN * 64, 256), b256, 0, stream>>>(x, conv1_w, dinv, xwsB);
  gcn_csr_k<<<cdiv(NN, 4), b256, 0, stream>>>(rowptr, esrc_s, xwsB, dinv, conv1_b, nodeB);

  // ---- GCN layer 2: MFMA (bf16 out, row-prescaled) -> CSR sum ----
  gemm_mfma_k<128, 128, true, false, true><<<dim3(MB, 1), b256, 0, stream>>>(
      (const unsigned short*)nodeB, conv2T, nullptr, dinv, xwsB, NN);
  gcn_csr_k<<<cdiv(NN, 4), b256, 0, stream>>>(rowptr, esrc_s, xwsB, dinv, conv2_b, nodeB);

  // ---- GRU -> txt bf16 ----
  gru_fused_k<<<NN / 32, b256, 0, stream>>>(xtext, embed, wihB, whhB, brz, binv, bhnv, txtB);

  // ---- node tables (bf16, combined src|dst cols) ----
  gemm_mfma_k<128, 256, true, true, false><<<dim3(MB, 2), b256, 0, stream>>>(
      (const unsigned short*)nodeB, TposW, bcomb, nullptr, Tall, NN);
  gemm_mfma_k<128, 256, true, true, false><<<dim3(MB, 2), b256, 0, stream>>>(
      txtB, TtxtW, bcomb + 256, nullptr, Tall + (size_t)NN * 256, NN);
  gemm_mfma_k<256, 256, true, true, false><<<dim3(MB, 2), b256, 0, stream>>>(
      imgB, TimgW, bcomb + 512, nullptr, Tall + (size_t)2 * NN * 256, NN);

  // ---- fused edge heads + log_softmax (dst-sorted order, XCD-swizzled) ----
  edge_mfma_k<<<NE / 128, b256, 0, stream>>>(esrc_s, edst_s, eorig_s, Tall,
                                             rw1T, rb1, rw2, rb2, cw1T, cb1, cw2, cb2, out);
}